// Round 3
// baseline (1442.733 us; speedup 1.0000x reference)
//
#include <hip/hip_runtime.h>

// Problem constants (from reference):
//   B=4, E=320000, N=10000, F=64
//   out[b, idx[b,e], :] += msg[b, e, :]   (scatter-add, duplicates sum)
//   h_v (d_in[2]) is unused except for shape.
#define B_ 4
#define E_ 320000
#define N_ 10000
#define F_ 64

// Native 4-float vector for __builtin_nontemporal_load (HIP_vector_type float4
// is a struct the builtin rejects).
typedef float floatx4 __attribute__((ext_vector_type(4)));

// One thread processes one float4 chunk (16 chunks per edge row of 64 floats).
// Wave of 64 lanes covers 4 edges; atomic addresses within a wave are 4
// distinct output rows x 16 strided float4 slots -> no intra-wave same-address
// serialization. unsafeAtomicAdd -> hardware global_atomic_add_f32 (resolves
// in L2; the 10.24 MB output is L2-resident).
// msg/idx are read-once streams -> nontemporal loads so they don't evict the
// hot output lines from the 4 MiB/XCD L2s.
__global__ __launch_bounds__(256) void scatter_add_f4(
    const floatx4* __restrict__ msg,  // [B*E*16] float4 view of [B,E,64]
    const int*     __restrict__ idx,  // [B*E]
    float*         __restrict__ out)  // [B*N*64]
{
    const int total = B_ * E_ * 16;                 // 20,480,000 float4 chunks
    const int stride = gridDim.x * blockDim.x;
    for (int w = blockIdx.x * blockDim.x + threadIdx.x; w < total; w += stride) {
        const int f4 = w & 15;          // which float4 within the 64-float row
        const int eg = w >> 4;          // global edge id in [0, B*E)
        const int b  = eg / E_;         // magic-mul division by constant
        const floatx4 v = __builtin_nontemporal_load(&msg[w]);
        const int node = __builtin_nontemporal_load(&idx[eg]);
        float* dst = out + (((long)b * N_ + node) * F_ + f4 * 4);
        unsafeAtomicAdd(dst + 0, v.x);
        unsafeAtomicAdd(dst + 1, v.y);
        unsafeAtomicAdd(dst + 2, v.z);
        unsafeAtomicAdd(dst + 3, v.w);
    }
}

extern "C" void kernel_launch(void* const* d_in, const int* in_sizes, int n_in,
                              void* d_out, int out_size, void* d_ws, size_t ws_size,
                              hipStream_t stream) {
    const float* msg = (const float*)d_in[0];   // [B,E,F] f32
    const int*   idx = (const int*)d_in[1];     // [B,E] i32
    // d_in[2] (h_v) unused.
    float* out = (float*)d_out;                 // [B,N,F] f32

    // Harness poisons d_out with 0xAA before every timed call -> zero it.
    (void)hipMemsetAsync(d_out, 0, (size_t)B_ * N_ * F_ * sizeof(float), stream);

    // 2048 blocks = 8 per CU; grid-stride covers 20.48M chunks (~39 iters/thread).
    scatter_add_f4<<<2048, 256, 0, stream>>>((const floatx4*)msg, idx, out);
}

// Round 5
// 639.196 us; speedup vs baseline: 2.2571x; 2.2571x over previous
//
#include <hip/hip_runtime.h>

// Problem: out[b, idx[b,e], :] += msg[b, e, :]  (B=4, E=320000, N=10000, F=64)
// Round-3 counters: 81.92M device-scope f32 atomics execute MEMORY-SIDE on
// multi-XCD CDNA4 (WRITE_SIZE = 16B x n_atomics = 1.31GB), rate ~75G/s ->
// 1090us atomic-bound. Fix: invert scatter->gather via counting sort on the
// 40000 (b,node) bins; only 2.56M int atomics remain, output written with one
// coalesced non-atomic store per row.
#define B_ 4
#define E_ 320000
#define N_ 10000
#define F_ 64
#define NBINS (B_ * N_)          // 40000
#define NEDGE (B_ * E_)          // 1,280,000
#define STRIP 40                 // ceil(40000/1024) bins per thread in scan

typedef float floatx4 __attribute__((ext_vector_type(4)));

// ---------- Phase 1: histogram of bin counts (bins must be pre-zeroed) ----
__global__ __launch_bounds__(256) void k_hist(const int* __restrict__ idx,
                                              int* __restrict__ bins) {
    const int eg = blockIdx.x * 256 + threadIdx.x;        // grid covers NEDGE exactly
    const int b = eg / E_;
    atomicAdd(&bins[b * N_ + idx[eg]], 1);
}

// ---------- Phase 2: exclusive scan over 40000 counts -> offs, cur ----------
__global__ __launch_bounds__(1024) void k_scan(const int* __restrict__ bins,
                                               int* __restrict__ offs,
                                               int* __restrict__ cur) {
    __shared__ int sums[1024];
    const int t = threadIdx.x;
    const int base = t * STRIP;
    int c[STRIP];
    int total = 0;
#pragma unroll
    for (int k = 0; k < STRIP; ++k) {
        const int i = base + k;
        c[k] = (i < NBINS) ? bins[i] : 0;
        total += c[k];
    }
    sums[t] = total;
    __syncthreads();
    // Hillis-Steele inclusive scan over the 1024 strip totals.
    for (int d = 1; d < 1024; d <<= 1) {
        const int v = (t >= d) ? sums[t - d] : 0;
        __syncthreads();
        sums[t] += v;
        __syncthreads();
    }
    int run = (t == 0) ? 0 : sums[t - 1];
#pragma unroll
    for (int k = 0; k < STRIP; ++k) {
        const int i = base + k;
        if (i < NBINS) { offs[i] = run; cur[i] = run; }
        run += c[k];
    }
}

// ---------- Phase 3: build permutation perm[p] = edge id ----------
__global__ __launch_bounds__(256) void k_fill(const int* __restrict__ idx,
                                              int* __restrict__ cur,
                                              int* __restrict__ perm) {
    const int eg = blockIdx.x * 256 + threadIdx.x;        // grid covers NEDGE exactly
    const int b = eg / E_;
    const int p = atomicAdd(&cur[b * N_ + idx[eg]], 1);
    perm[p] = eg;
}

// ---------- Phase 4: gather-accumulate, one wave per output row ----------
__global__ __launch_bounds__(256) void k_gather(const float* __restrict__ msg,
                                                const int* __restrict__ perm,
                                                const int* __restrict__ offs,
                                                const int* __restrict__ cur,
                                                float* __restrict__ out) {
    const int gtid = blockIdx.x * 256 + threadIdx.x;
    const int r = gtid >> 6;                              // wave id = output row
    const int l = threadIdx.x & 63;                       // lane = feature
    if (r >= NBINS) return;
    const int off = offs[r];
    const int cnt = cur[r] - off;                         // cur = end after fill
    float a0 = 0.f, a1 = 0.f, a2 = 0.f, a3 = 0.f;
    for (int basej = 0; basej < cnt; basej += 64) {
        const int m = min(64, cnt - basej);
        // Prefetch up to 64 edge ids, one per lane; broadcast via shfl.
        const int e = (l < m) ? perm[off + basej + l] : 0;
        int j = 0;
        for (; j + 4 <= m; j += 4) {
            const int e0 = __shfl(e, j, 64), e1 = __shfl(e, j + 1, 64);
            const int e2 = __shfl(e, j + 2, 64), e3 = __shfl(e, j + 3, 64);
            const float v0 = msg[(size_t)e0 * F_ + l];
            const float v1 = msg[(size_t)e1 * F_ + l];
            const float v2 = msg[(size_t)e2 * F_ + l];
            const float v3 = msg[(size_t)e3 * F_ + l];
            a0 += v0; a1 += v1; a2 += v2; a3 += v3;
        }
        for (; j < m; ++j)
            a0 += msg[(size_t)__shfl(e, j, 64) * F_ + l];
    }
    out[(size_t)r * F_ + l] = (a0 + a1) + (a2 + a3);
}

// ---------- Fallback (ws too small): round-3 atomic scatter ----------
__global__ __launch_bounds__(256) void scatter_add_f4(
    const floatx4* __restrict__ msg, const int* __restrict__ idx,
    float* __restrict__ out) {
    const int total = NEDGE * 16;
    const int stride = gridDim.x * blockDim.x;
    for (int w = blockIdx.x * blockDim.x + threadIdx.x; w < total; w += stride) {
        const int f4 = w & 15;
        const int eg = w >> 4;
        const int b = eg / E_;
        const floatx4 v = __builtin_nontemporal_load(&msg[w]);
        const int node = __builtin_nontemporal_load(&idx[eg]);
        float* dst = out + (((long)b * N_ + node) * F_ + f4 * 4);
        unsafeAtomicAdd(dst + 0, v.x);
        unsafeAtomicAdd(dst + 1, v.y);
        unsafeAtomicAdd(dst + 2, v.z);
        unsafeAtomicAdd(dst + 3, v.w);
    }
}

extern "C" void kernel_launch(void* const* d_in, const int* in_sizes, int n_in,
                              void* d_out, int out_size, void* d_ws, size_t ws_size,
                              hipStream_t stream) {
    const float* msg = (const float*)d_in[0];   // [B,E,F] f32
    const int*   idx = (const int*)d_in[1];     // [B,E] i32
    float* out = (float*)d_out;                 // [B,N,F] f32

    // Workspace layout (ints): bins[40000] | offs[40000] | cur[40000] | perm[1280000]
    const size_t need = (size_t)(NBINS * 3 + NEDGE) * sizeof(int);   // 5.6 MB
    if (ws_size < need) {
        // Fallback: atomic scatter (slow but correct).
        (void)hipMemsetAsync(d_out, 0, (size_t)NBINS * F_ * sizeof(float), stream);
        scatter_add_f4<<<2048, 256, 0, stream>>>((const floatx4*)msg, idx, out);
        return;
    }

    int* bins = (int*)d_ws;
    int* offs = bins + NBINS;
    int* cur  = offs + NBINS;
    int* perm = cur + NBINS;

    // ws is re-poisoned 0xAA before every timed call -> zero the histogram.
    (void)hipMemsetAsync(bins, 0, (size_t)NBINS * sizeof(int), stream);

    k_hist<<<NEDGE / 256, 256, 0, stream>>>(idx, bins);
    k_scan<<<1, 1024, 0, stream>>>(bins, offs, cur);
    k_fill<<<NEDGE / 256, 256, 0, stream>>>(idx, cur, perm);
    // 40000 rows, 4 waves per 256-thread block -> 10000 blocks. Gather writes
    // every output row (zeros for empty bins) -> no d_out memset needed.
    k_gather<<<NBINS / 4, 256, 0, stream>>>(msg, perm, offs, cur, out);
}